// Round 3
// baseline (418.586 us; speedup 1.0000x reference)
//
#include <hip/hip_runtime.h>

// SplitLinear: out[b, o*C + c] = sum_s x[b, s*C + c] * w[o, s, c] + bias[o*C + c]
// x: [64, 1e6] fp32, w: [4, 400, 2500] fp32, bias: [10000], out: [64, 10000]
//
// R9: R0-R2 deltas each matched kernel-side traffic arithmetic 1:1 =>
// timed region = ~310 us fixed harness fills + ~57 us of my kernels, and
// the R2 kernel pair runs at ~88% of its STRUCTURAL roofline (315 MB).
// Remaining waste is the ws round-trip + reduce kernel (43.5 MB + launch
// ~= 10 us). Absolute floor = x 256 + w 16 + out 2.5 = 274.5 MB ~= 44 us.
// Fix: keep the NSPLIT=8 / z=wg%8 structure (each XCD L2 privately holds
// one 2 MB w-slice -- the property that makes w re-reads free) but replace
// ws+sl_reduce with device-scope fp32 atomicAdd into out, pre-filled with
// bias. out (2.5 MB) stays MALL-resident; 5.1M atomics / ~45 us with only
// 8 contributors per line. If atomics serialize (dur regresses), revert to
// two-kernel NSPLIT=4 next.

constexpr int IN_F   = 1000000;
constexpr int S_DIM  = 400;
constexpr int C_DIM  = 2500;
constexpr int O_SETS = 4;
constexpr int B_SZ   = 64;
constexpr int OC     = O_SETS * C_DIM;    // 10000
constexpr int OUT_N  = B_SZ * OC;         // 640000

constexpr int NQ      = C_DIM / 4;        // 625 float4 quads per s-row
constexpr int THREADS = 640;              // 10 waves, covers one full s-row
constexpr int NSPLIT  = 8;                // s segments, one per XCD
constexpr int SSEG    = S_DIM / NSPLIT;   // 50 s-steps per segment
constexpr int BT      = 2;                // b rows per thread
constexpr int BGRP    = B_SZ / BT;        // 32
constexpr int STEPQ   = NQ;               // float4 stride per s-step (contig)

typedef float f4 __attribute__((ext_vector_type(4)));

__device__ __forceinline__ f4 ntload(const f4* p) {
    return __builtin_nontemporal_load(p);
}

__device__ __forceinline__ void fma4(f4& a, f4 p, f4 q) {
    a.x = fmaf(p.x, q.x, a.x);
    a.y = fmaf(p.y, q.y, a.y);
    a.z = fmaf(p.z, q.z, a.z);
    a.w = fmaf(p.w, q.w, a.w);
}

// ---------------- out = bias (broadcast over b) ----------------
// OUT_N/4 = 160000 quads, 625 blocks of 256 thr. OC % 4 == 0 so a quad
// never crosses a b-row.
__global__ __launch_bounds__(256) void sl_bias_init(const float* __restrict__ bias,
                                                    float* __restrict__ out) {
    const int t = blockIdx.x * 256 + threadIdx.x;
    if (t >= OUT_N / 4) return;
    const int idx = t * 4;
    const int oc  = idx % OC;
    *(f4*)(out + idx) = *(const f4*)(bias + oc);
}

// ---------------- Main: partial sums via atomics ----------------
// grid (NSPLIT, BGRP), block = 640 thr. Thread tid -> c-quad tid (block
// spans one complete 10 KB s-row); BT=2 b-rows, 4 o-sets, acc over SSEG=50
// s-steps. z = blockIdx.x -> wg%8 -> one 2 MB w-slice per XCD L2.
// Epilogue: 32 fp32 atomicAdds per thread into bias-initialized out.
__global__ __launch_bounds__(THREADS, 3) void sl_part_atomic(const float* __restrict__ x,
                                                             const float* __restrict__ w,
                                                             float* __restrict__ out) {
    const int tid = threadIdx.x;
    const bool act = (tid < NQ);
    const int q   = act ? tid : NQ - 1;   // clamp: junk loads stay in-bounds
    const int z   = blockIdx.x;
    const int b0  = blockIdx.y * BT;
    const int s0  = z * SSEG;

    const f4* xp[BT];
#pragma unroll
    for (int i = 0; i < BT; ++i)
        xp[i] = (const f4*)(x + (size_t)(b0 + i) * IN_F + (size_t)s0 * C_DIM) + q;

    const f4* wp[O_SETS];
#pragma unroll
    for (int o = 0; o < O_SETS; ++o)
        wp[o] = (const f4*)(w + (size_t)o * (S_DIM * C_DIM) + (size_t)s0 * C_DIM) + q;

    f4 acc[BT][O_SETS];
#pragma unroll
    for (int i = 0; i < BT; ++i)
#pragma unroll
        for (int o = 0; o < O_SETS; ++o)
            acc[i][o] = (f4)(0.f);

    // Depth-3 rotation: 18 loads (~18 KB/wave) in flight while 32 fma run.
    // All indices compile-time after full unroll.
    f4 xb[3][BT], wb[3][O_SETS];
#pragma unroll
    for (int p = 0; p < 2; ++p) {
#pragma unroll
        for (int i = 0; i < BT; ++i) { xb[p][i] = ntload(xp[i]); xp[i] += STEPQ; }
#pragma unroll
        for (int o = 0; o < O_SETS; ++o) { wb[p][o] = *wp[o]; wp[o] += STEPQ; }
    }

#pragma unroll
    for (int s = 0; s < SSEG; ++s) {
        const int cur = s % 3;
        const int nxt = (s + 2) % 3;
        if (s + 2 < SSEG) {   // compile-time after full unroll
#pragma unroll
            for (int i = 0; i < BT; ++i) { xb[nxt][i] = ntload(xp[i]); xp[i] += STEPQ; }
#pragma unroll
            for (int o = 0; o < O_SETS; ++o) { wb[nxt][o] = *wp[o]; wp[o] += STEPQ; }
        }
#pragma unroll
        for (int i = 0; i < BT; ++i)
#pragma unroll
            for (int o = 0; o < O_SETS; ++o)
                fma4(acc[i][o], xb[cur][i], wb[cur][o]);
    }

    if (act) {
#pragma unroll
        for (int i = 0; i < BT; ++i) {
            float* orow = out + (size_t)(b0 + i) * OC;
#pragma unroll
            for (int o = 0; o < O_SETS; ++o) {
                float* dst = orow + o * C_DIM + q * 4;
                atomicAdd(dst + 0, acc[i][o].x);
                atomicAdd(dst + 1, acc[i][o].y);
                atomicAdd(dst + 2, acc[i][o].z);
                atomicAdd(dst + 3, acc[i][o].w);
            }
        }
    }
}

extern "C" void kernel_launch(void* const* d_in, const int* in_sizes, int n_in,
                              void* d_out, int out_size, void* d_ws, size_t ws_size,
                              hipStream_t stream) {
    const float* x    = (const float*)d_in[0];
    const float* wgt  = (const float*)d_in[1];
    const float* bias = (const float*)d_in[2];
    float* out = (float*)d_out;

    // out = bias, then NSPLIT partial GEMVs atomically accumulate.
    // Same-stream launches serialize: init completes before atomics start.
    sl_bias_init<<<(OUT_N / 4 + 255) / 256, 256, 0, stream>>>(bias, out);
    dim3 g(NSPLIT, BGRP);
    sl_part_atomic<<<g, THREADS, 0, stream>>>(x, wgt, out);
}

// Round 4
// 386.128 us; speedup vs baseline: 1.0841x; 1.0841x over previous
//
#include <hip/hip_runtime.h>

// SplitLinear: out[b, o*C + c] = sum_s x[b, s*C + c] * w[o, s, c] + bias[o*C + c]
// x: [64, 1e6] fp32, w: [4, 400, 2500] fp32, bias: [10000], out: [64, 10000]
//
// R10: R3's atomic epilogue cost +52 us (fp32 global atomicAdd ~10 ns each,
// memory-side serialization) -> reverted to R2's two-kernel ws+reduce
// structure, which runs ~88% of structural roofline. Remaining discretionary
// traffic is the ws round-trip (prop. to NSPLIT). This round: NSPLIT 8->4
// (ws 41->20.5 MB round-trip, reduce reads halve), BT 2->1 to keep the grid
// at 256 blocks (grid (4,64), 640 thr). wg%8 -> each XCD gets one fixed
// (z, y-parity): a single 4 MB w-slice per XCD L2, kept resident by nt-
// tagged x loads (R2's proven win). Depth-3 register prefetch unchanged.

constexpr int IN_F   = 1000000;
constexpr int S_DIM  = 400;
constexpr int C_DIM  = 2500;
constexpr int O_SETS = 4;
constexpr int B_SZ   = 64;
constexpr int OC     = O_SETS * C_DIM;    // 10000
constexpr int OUT_N  = B_SZ * OC;         // 640000

constexpr int NQ      = C_DIM / 4;        // 625 float4 quads per s-row
constexpr int THREADS = 640;              // 10 waves, covers one full s-row
constexpr int NSPLIT  = 4;                // s segments
constexpr int SSEG    = S_DIM / NSPLIT;   // 100 s-steps per segment
constexpr int BT      = 1;                // b rows per thread
constexpr int BGRP    = B_SZ / BT;        // 64
constexpr int STEPQ   = NQ;               // float4 stride per s-step (contig)

constexpr size_t WS_NEED = (size_t)NSPLIT * OUT_N * sizeof(float);  // 10.25 MB

typedef float f4 __attribute__((ext_vector_type(4)));

__device__ __forceinline__ f4 ntload(const f4* p) {
    return __builtin_nontemporal_load(p);
}

__device__ __forceinline__ void fma4(f4& a, f4 p, f4 q) {
    a.x = fmaf(p.x, q.x, a.x);
    a.y = fmaf(p.y, q.y, a.y);
    a.z = fmaf(p.z, q.z, a.z);
    a.w = fmaf(p.w, q.w, a.w);
}

// ---------------- Main path ----------------

// grid (NSPLIT, BGRP), block = 640 thr. Thread tid -> c-quad tid (block spans
// one complete 10 KB s-row); BT=1 b-row, 4 o-sets, acc over SSEG=100 s-steps.
// All 5 read streams advance contiguously by 10 KB/step.
__global__ __launch_bounds__(THREADS, 3) void sl_part(const float* __restrict__ x,
                                                      const float* __restrict__ w,
                                                      float* __restrict__ ws) {
    const int tid = threadIdx.x;
    const bool act = (tid < NQ);
    const int q   = act ? tid : NQ - 1;   // clamp: junk loads stay in-bounds
    const int z   = blockIdx.x;
    const int b0  = blockIdx.y;           // BT = 1
    const int s0  = z * SSEG;

    const f4* xp = (const f4*)(x + (size_t)b0 * IN_F + (size_t)s0 * C_DIM) + q;

    const f4* wp[O_SETS];
#pragma unroll
    for (int o = 0; o < O_SETS; ++o)
        wp[o] = (const f4*)(w + (size_t)o * (S_DIM * C_DIM) + (size_t)s0 * C_DIM) + q;

    f4 acc[O_SETS];
#pragma unroll
    for (int o = 0; o < O_SETS; ++o) acc[o] = (f4)(0.f);

    // Depth-3 rotation: 10 loads (~10 KB/wave) in flight while 16 fma run.
    // All indices compile-time after full unroll.
    f4 xb[3], wb[3][O_SETS];
#pragma unroll
    for (int p = 0; p < 2; ++p) {
        xb[p] = ntload(xp); xp += STEPQ;
#pragma unroll
        for (int o = 0; o < O_SETS; ++o) { wb[p][o] = *wp[o]; wp[o] += STEPQ; }
    }

#pragma unroll
    for (int s = 0; s < SSEG; ++s) {
        const int cur = s % 3;
        const int nxt = (s + 2) % 3;
        if (s + 2 < SSEG) {   // compile-time after full unroll
            xb[nxt] = ntload(xp); xp += STEPQ;
#pragma unroll
            for (int o = 0; o < O_SETS; ++o) { wb[nxt][o] = *wp[o]; wp[o] += STEPQ; }
        }
#pragma unroll
        for (int o = 0; o < O_SETS; ++o)
            fma4(acc[o], xb[cur], wb[cur][o]);
    }

    if (act) {
        float* orow = ws + (size_t)z * OUT_N + (size_t)b0 * OC;
#pragma unroll
        for (int o = 0; o < O_SETS; ++o)
            __builtin_nontemporal_store(acc[o], (f4*)(orow + o * C_DIM + q * 4));
    }
}

// out[idx] = bias[idx % OC] + sum_z ws[z][idx]
__global__ __launch_bounds__(256) void sl_reduce(const float* __restrict__ ws,
                                                 const float* __restrict__ bias,
                                                 float* __restrict__ out) {
    const int t = blockIdx.x * 256 + threadIdx.x;
    if (t >= OUT_N / 4) return;
    const int idx = t * 4;
    const int oc  = idx % OC;   // OC % 4 == 0 -> a float4 never crosses rows

    f4 s0 = *(const f4*)(bias + oc);
    f4 s1 = (f4)(0.f);
#pragma unroll
    for (int z = 0; z < NSPLIT; z += 2) {
        f4 v0 = ntload((const f4*)(ws + (size_t)z * OUT_N + idx));
        f4 v1 = ntload((const f4*)(ws + (size_t)(z + 1) * OUT_N + idx));
        s0.x += v0.x; s0.y += v0.y; s0.z += v0.z; s0.w += v0.w;
        s1.x += v1.x; s1.y += v1.y; s1.z += v1.z; s1.w += v1.w;
    }
    s0.x += s1.x; s0.y += s1.y; s0.z += s1.z; s0.w += s1.w;
    __builtin_nontemporal_store(s0, (f4*)(out + idx));
}

// ---------------- Fallback (ws too small): atomics ----------------

__global__ __launch_bounds__(256) void sl_init(const float* __restrict__ bias,
                                               float* __restrict__ out) {
    int j = blockIdx.x * 256 + threadIdx.x;
    if (j < OC) out[(size_t)blockIdx.y * OC + j] = bias[j];
}

__global__ __launch_bounds__(64) void sl_atomic(const float* __restrict__ x,
                                                const float* __restrict__ w,
                                                float* __restrict__ out) {
    const int lane = threadIdx.x;
    const int qq   = blockIdx.x * 64 + lane;
    if (qq >= NQ) return;
    const int b  = blockIdx.y;
    const int s0 = blockIdx.z * SSEG;

    const f4* xp = (const f4*)(x + (size_t)b * IN_F + (size_t)s0 * C_DIM) + qq;
    const f4* wp[O_SETS];
#pragma unroll
    for (int o = 0; o < O_SETS; ++o)
        wp[o] = (const f4*)(w + (size_t)o * (S_DIM * C_DIM) + (size_t)s0 * C_DIM) + qq;

    f4 acc[O_SETS];
#pragma unroll
    for (int o = 0; o < O_SETS; ++o) acc[o] = (f4)(0.f);

    for (int s = 0; s < SSEG; ++s) {
        f4 xv = *xp; xp += STEPQ;
        f4 wv4[O_SETS];
#pragma unroll
        for (int o = 0; o < O_SETS; ++o) { wv4[o] = *wp[o]; wp[o] += STEPQ; }
#pragma unroll
        for (int o = 0; o < O_SETS; ++o) fma4(acc[o], xv, wv4[o]);
    }

    float* orow = out + (size_t)b * OC;
#pragma unroll
    for (int o = 0; o < O_SETS; ++o) {
        float* dst = orow + o * C_DIM + qq * 4;
        atomicAdd(dst + 0, acc[o].x);
        atomicAdd(dst + 1, acc[o].y);
        atomicAdd(dst + 2, acc[o].z);
        atomicAdd(dst + 3, acc[o].w);
    }
}

extern "C" void kernel_launch(void* const* d_in, const int* in_sizes, int n_in,
                              void* d_out, int out_size, void* d_ws, size_t ws_size,
                              hipStream_t stream) {
    const float* x    = (const float*)d_in[0];
    const float* wgt  = (const float*)d_in[1];
    const float* bias = (const float*)d_in[2];
    float* out = (float*)d_out;

    if (ws_size >= WS_NEED) {
        float* ws = (float*)d_ws;
        dim3 g(NSPLIT, BGRP);
        sl_part<<<g, THREADS, 0, stream>>>(x, wgt, ws);
        sl_reduce<<<(OUT_N / 4 + 255) / 256, 256, 0, stream>>>(ws, bias, out);
    } else {
        dim3 gInit((OC + 255) / 256, B_SZ);
        sl_init<<<gInit, 256, 0, stream>>>(bias, out);
        dim3 g((NQ + 63) / 64, B_SZ, NSPLIT);
        sl_atomic<<<g, 64, 0, stream>>>(x, wgt, out);
    }
}